// Round 3
// baseline (120.778 us; speedup 1.0000x reference)
//
#include <hip/hip_runtime.h>

#define R_DIM 2048
#define O_DIM 32
#define I_DIM 16
#define B_DIM 64
#define BB 16   // batch rows per block

typedef _Float16 half4  __attribute__((ext_vector_type(4)));
typedef float    f32x4  __attribute__((ext_vector_type(4)));
typedef float    f32x2  __attribute__((ext_vector_type(2)));

struct SplitH4 { half4 h1, h2; };

// 2-way fp16 split of 4 consecutive fp32: x = h1 + h2 + O(2^-22 * x).
// Proven primitive sequence (cvt_pkrtz + f32 sub + cvt_pkrtz).
__device__ __forceinline__ SplitH4 splitf16x4(const float* __restrict__ p) {
    const float4 f = *(const float4*)p;
    const auto a0 = __builtin_amdgcn_cvt_pkrtz(f.x, f.y);
    const auto a1 = __builtin_amdgcn_cvt_pkrtz(f.z, f.w);
    const auto c0 = __builtin_amdgcn_cvt_pkrtz(f.x - (float)a0[0], f.y - (float)a0[1]);
    const auto c1 = __builtin_amdgcn_cvt_pkrtz(f.z - (float)a1[0], f.w - (float)a1[1]);
    SplitH4 s;
    s.h1[0] = (_Float16)a0[0]; s.h1[1] = (_Float16)a0[1];
    s.h1[2] = (_Float16)a1[0]; s.h1[3] = (_Float16)a1[1];
    s.h2[0] = (_Float16)c0[0]; s.h2[1] = (_Float16)c0[1];
    s.h2[2] = (_Float16)c1[0]; s.h2[3] = (_Float16)c1[1];
    return s;
}

// DPP helpers — all stay on the VALU pipe (no DS traffic).
template<int CTRL>
__device__ __forceinline__ float dpp_mv(float v) {
    int t = __builtin_amdgcn_update_dpp(0, __float_as_int(v), CTRL, 0xf, 0xf, true);
    return __int_as_float(t);
}
__device__ __forceinline__ float row16_sum(float v) {
    v += dpp_mv<0xB1>(v);    // quad_perm xor1
    v += dpp_mv<0x4E>(v);    // quad_perm xor2
    v += dpp_mv<0x124>(v);   // row_ror:4
    v += dpp_mv<0x128>(v);   // row_ror:8
    return v;
}
__device__ __forceinline__ float row16_max(float v) {
    v = fmaxf(v, dpp_mv<0xB1>(v));
    v = fmaxf(v, dpp_mv<0x4E>(v));
    v = fmaxf(v, dpp_mv<0x124>(v));
    v = fmaxf(v, dpp_mv<0x128>(v));
    return v;
}
// row_ror:N — dst[n] = src[(n-N)&15]
__device__ __forceinline__ float ror1(float v) { return dpp_mv<0x121>(v); }
__device__ __forceinline__ float ror8(float v) { return dpp_mv<0x128>(v); }
__device__ __forceinline__ float ror9(float v) { return dpp_mv<0x129>(v); }

// Plain (modifier-free) packed fp32 ops — unambiguous elementwise semantics.
__device__ __forceinline__ void pk_fma(f32x2& d, const f32x2 a, const f32x2 b) {
    asm("v_pk_fma_f32 %0, %1, %2, %0" : "+v"(d) : "v"(a), "v"(b));
}
__device__ __forceinline__ void pk_add(f32x2& d, const f32x2 a) {
    asm("v_pk_add_f32 %0, %1, %0" : "+v"(d) : "v"(a));
}

// Block: 512 threads = 8 waves; one (r, 16-batch slice); 32 KB LDS ->
// 4 blocks/CU = 32 waves/CU cap.
// Phase 1 (all 8 waves): u_hat[16b x 512n] via 3-term fp16-split MFMA 16x16x16.
// Phase 2 (first 256 lanes): thread=(b,j) owns o={2j,2j+1}; lane j holds
//   logit bv[c=j]; stride-1 dual systolic chains in PACKED fp32:
//   X[m] = {u[c=j-m][o0], u[c=j-m-8][o0]}, Y[m] likewise for o1.
// Swizzle: addr = row*512 + (n ^ sw), sw = ((row^(row>>2))&3)<<3 | (row&1).
//   The parity bit puts odd rows on odd banks -> phase-2 b32 reads are 2-way
//   (free) instead of the old b64 4-way aliasing.
__global__ __launch_bounds__(512, 8)
void capsule_routing_kernel(const float* __restrict__ x,
                            const float* __restrict__ W,
                            float* __restrict__ out) {
    __shared__ float u_lds[BB * 512];   // 32 KB

    const int tid = threadIdx.x;
    // XCD-grouping remap: the 4 batch-slice blocks of one r land on one XCD.
    const int bid = blockIdx.x;
    const int r   = ((bid >> 5) << 3) | (bid & 7);
    const int b0  = ((bid >> 3) & 3) * BB;

    // ---------------- Phase 1: fp16-split MFMA u_hat ----------------
    {
        const int lane = tid & 63;
        const int w    = tid >> 6;     // wave 0..7 -> n-tiles 4w..4w+3
        const int q    = lane >> 4;    // k-quad 0..3 (all valid, K=16)
        const int np   = lane & 15;    // m (batch) for A / n-col for B

        const SplitH4 as = splitf16x4(x + ((size_t)(b0 + np) * R_DIM + r) * I_DIM + q * 4);

        const float* Wbase = W + (size_t)r * 8192 + (size_t)(w * 4) * 256 + np * 16 + q * 4;

        const f32x4 zero4 = {0.f, 0.f, 0.f, 0.f};
        #pragma unroll
        for (int t = 0; t < 4; ++t) {
            const int ntile = w * 4 + t;
            const SplitH4 bs = splitf16x4(Wbase + t * 256);

            f32x4 a = __builtin_amdgcn_mfma_f32_16x16x16f16(as.h2, bs.h1, zero4, 0, 0, 0);
            a = __builtin_amdgcn_mfma_f32_16x16x16f16(as.h1, bs.h2, a, 0, 0, 0);
            a = __builtin_amdgcn_mfma_f32_16x16x16f16(as.h1, bs.h1, a, 0, 0, 0);

            // row = 4q+reg; sw = ((reg^q)&3)<<3 | (reg&1)
            const int col = ntile * 16 + np;
            const int v0  = col ^ (q << 3);
            float* pb = u_lds + q * 2048;
            pb[v0]               = a[0];
            pb[512  + (v0 ^ 9)]  = a[1];
            pb[1024 + (v0 ^ 16)] = a[2];
            pb[1536 + (v0 ^ 25)] = a[3];
        }
    }
    __syncthreads();

    // ---------------- Phase 2: systolic dynamic routing (lanes 0-255) ----------
    if (tid < 256) {
        const int b = tid >> 4;    // 0..15 local batch (one DPP row per b)
        const int j = tid & 15;    // o-pair index / owner of logit c=j

        const int sw = (((b ^ (b >> 2)) & 3) << 3) | (b & 1);
        // byte addresses of o0/o1 at c=0 for this thread
        const int px = (b * 512 + ((2 * j) ^ sw)) * 4;
        const int py = (b * 512 + ((2 * j + 1) ^ sw)) * 4;
        const char* base = (const char*)u_lds;

        // X[m] = {u[c=(j-m)&15][o0], u[c=(j-m-8)&15][o0]}; Y[m]: same for o1.
        // c-field = addr bits 7..10; running t wraps via &0x780 (two's-compl ok);
        // c-8 (mod 16) == c-field ^ 0x400.
        f32x2 X[8], Y[8];
        {
            int t = j * 128;
            #pragma unroll
            for (int m = 0; m < 8; ++m) {
                const int a1 = t & 0x780;
                const int a2 = a1 ^ 0x400;
                X[m].x = *(const float*)(base + (a1 | px));
                X[m].y = *(const float*)(base + (a2 | px));
                Y[m].x = *(const float*)(base + (a1 | py));
                Y[m].y = *(const float*)(base + (a2 | py));
                t -= 128;
            }
        }

        float bvv = 0.0f;          // logit for c=j (distributed)
        float s0 = 0.f, s1 = 0.f, g = 0.f;

        #pragma unroll
        for (int it = 0; it < 3; ++it) {
            if (it == 0) {
                // uniform weights: mean over c, packed adds
                f32x2 P0 = X[0], P1 = Y[0];
                #pragma unroll
                for (int m = 1; m < 8; ++m) { pk_add(P0, X[m]); pk_add(P1, Y[m]); }
                s0 = (P0.x + P0.y) * 0.0625f;
                s1 = (P1.x + P1.y) * 0.0625f;
            } else {
                // softmax at lane c: 1 exp/thread
                const float mx = row16_max(bvv);
                const float e  = __expf(bvv - mx);
                const float Z  = row16_sum(e);
                const float wr = e * __builtin_amdgcn_rcpf(Z);   // w_c at lane c
                // s_o = sum_c w_c u[c][o]; W2 = {w_{j-m}, w_{j-m-8}} per step
                f32x2 W2; W2.x = wr; W2.y = ror8(wr);
                f32x2 P0; P0.x = 0.f; P0.y = 0.f;
                f32x2 P1; P1.x = 0.f; P1.y = 0.f;
                #pragma unroll
                for (int m = 0; m < 8; ++m) {
                    if (m) { W2.x = ror1(W2.x); W2.y = ror1(W2.y); }
                    pk_fma(P0, X[m], W2);
                    pk_fma(P1, Y[m], W2);
                }
                s0 = P0.x + P0.y;
                s1 = P1.x + P1.y;
            }

            // g = ||s|| / (1 + ||s||^2), norm over 32 o's (16 j-lanes x 2)
            const float nn = row16_sum(fmaf(s0, s0, s1 * s1));
            g = sqrtf(nn) * __builtin_amdgcn_rcpf(1.0f + nn);

            if (it < 2) {
                // t[c] = sum_o u[c][o] s[o] via packed rotating accumulator.
                // ACC.lo: chain A (c=j-m), ACC.hi: chain B (c=j-m-8).
                // Term m needs total rot 16-m (A) / 8-m (B); loop gives 7-m;
                // finals: ror9(lo), ror1(hi).
                f32x2 S0p; S0p.x = s0; S0p.y = s0;
                f32x2 S1p; S1p.x = s1; S1p.y = s1;
                f32x2 ACC; ACC.x = 0.f; ACC.y = 0.f;
                #pragma unroll
                for (int m = 0; m < 8; ++m) {
                    if (m) { ACC.x = ror1(ACC.x); ACC.y = ror1(ACC.y); }
                    pk_fma(ACC, X[m], S0p);
                    pk_fma(ACC, Y[m], S1p);
                }
                const float acc = ror9(ACC.x) + ror1(ACC.y);
                bvv = fmaf(g, acc, bvv);   // b[c] += g * t[c]
            }
        }

        *(float2*)(out + ((size_t)(b0 + b) * R_DIM + r) * O_DIM + 2 * j)
            = make_float2(g * s0, g * s1);
    }
}

extern "C" void kernel_launch(void* const* d_in, const int* in_sizes, int n_in,
                              void* d_out, int out_size, void* d_ws, size_t ws_size,
                              hipStream_t stream) {
    const float* x   = (const float*)d_in[0];   // [64, 2048, 16]
    const float* W   = (const float*)d_in[1];   // [2048, 16, 32, 16]
    float*       out = (float*)d_out;           // [64, 2048, 32]

    dim3 grid(R_DIM * (B_DIM / BB));            // 8192 blocks
    dim3 block(512);
    hipLaunchKernelGGL(capsule_routing_kernel, grid, block, 0, stream, x, W, out);
}